// Round 6
// baseline (1750.996 us; speedup 1.0000x reference)
//
#include <hip/hip_runtime.h>

typedef unsigned short u16;
typedef unsigned int   u32;
typedef __attribute__((ext_vector_type(8))) short bf16x8;  // 8 bf16 (4 VGPRs)
typedef __attribute__((ext_vector_type(4))) float f32x4;   // 4 fp32

// ---------- bf16 helpers (manual, RNE) ----------
__device__ __forceinline__ float bf2f(u16 u) { return __uint_as_float(((u32)u) << 16); }
__device__ __forceinline__ float bflo(u32 u) { return __uint_as_float(u << 16); }
__device__ __forceinline__ float bfhi(u32 u) { return __uint_as_float(u & 0xffff0000u); }
__device__ __forceinline__ u16 f2bf(float f) {
    u32 x = __float_as_uint(f);
    x += 0x7fffu + ((x >> 16) & 1u);   // round-to-nearest-even
    return (u16)(x >> 16);
}

// ---------- repack conv2 weights: w2r[kk][ccc][h][co][cil], h=0 hi plane, h=1 lo plane ----------
// error-compensated bf16: w ~= hi + lo, two MFMAs per chunk recover ~fp32 weight precision
__global__ __launch_bounds__(256) void repack_w2_kernel(const float* __restrict__ w2,
                                                        u16* __restrict__ w2r) {
    int idx = blockIdx.x * 256 + threadIdx.x;      // 81*8*2*256*32 = 10,616,832
    int cil = idx & 31;
    int co  = (idx >> 5) & 255;
    int h   = (idx >> 13) & 1;
    int ccc = (idx >> 14) & 7;
    int kk  = idx >> 17;
    int ci  = ccc * 32 + cil;
    float v = w2[(size_t)co * 20736 + (size_t)ci * 81 + kk];
    u16 hi = f2bf(v);
    w2r[idx] = h ? f2bf(v - bf2f(hi)) : hi;
}

// ---------- repack W: Wt2[i][je][d] f32 from W[j][i][d][e] ----------
__global__ __launch_bounds__(256) void repack_W_kernel(const float* __restrict__ W,
                                                       float* __restrict__ Wt2) {
    int idx = blockIdx.x * 256 + threadIdx.x;      // total 1152*160*8 = 1,474,560
    int d  = idx & 7;
    int je = (idx >> 3) % 160;
    int i  = idx / 1280;
    int j = je >> 4, e = je & 15;
    Wt2[idx] = W[(((size_t)j * 1152 + i) * 8 + d) * 16 + e];
}

// ---------- conv1 (9x9 s1) + bias + bf16 store [b][p][co] + BN1 stats ----------
__global__ __launch_bounds__(256) void conv1_kernel(const float* __restrict__ x,
                                                    const float* __restrict__ w1,
                                                    const float* __restrict__ b1,
                                                    u16* __restrict__ y,
                                                    float* __restrict__ sum1,
                                                    float* __restrict__ sumsq1) {
    __shared__ float xs[784];
    const int b = blockIdx.x;
    const int t = threadIdx.x;          // co
    const float* xb = x + (size_t)b * 784;
    for (int idx = t; idx < 784; idx += 256) xs[idx] = xb[idx];
    float w[81];
#pragma unroll
    for (int q = 0; q < 81; ++q) w[q] = w1[(size_t)t * 81 + q];
    const float bias = b1[t];
    __syncthreads();

    float sl = 0.f, ssl = 0.f;
    u16* yb = y + (size_t)b * 400 * 256 + t;     // channels-last, stride 256
    for (int oh = 0; oh < 20; ++oh) {
        float acc[20];
#pragma unroll
        for (int ow = 0; ow < 20; ++ow) acc[ow] = bias;
#pragma unroll
        for (int kh = 0; kh < 9; ++kh) {
            const float4* rp = (const float4*)(&xs[(oh + kh) * 28]);
            float r[28];
#pragma unroll
            for (int k4 = 0; k4 < 7; ++k4) {
                float4 f = rp[k4];
                r[k4 * 4 + 0] = f.x; r[k4 * 4 + 1] = f.y;
                r[k4 * 4 + 2] = f.z; r[k4 * 4 + 3] = f.w;
            }
#pragma unroll
            for (int kw = 0; kw < 9; ++kw) {
                const float wv = w[kh * 9 + kw];
#pragma unroll
                for (int ow = 0; ow < 20; ++ow)
                    acc[ow] = fmaf(wv, r[ow + kw], acc[ow]);
            }
        }
#pragma unroll
        for (int ow = 0; ow < 20; ++ow) {
            u16 q = f2bf(acc[ow]);
            float rv = bf2f(q);
            sl += rv; ssl += rv * rv;
            yb[(size_t)(oh * 20 + ow) * 256] = q;
        }
    }
    atomicAdd(&sum1[t], sl);
    atomicAdd(&sumsq1[t], ssl);
}

// ---------- BN finalize: scale/shift from sums ----------
__global__ void finalize_bn_kernel(const float* __restrict__ sum,
                                   const float* __restrict__ sumsq,
                                   const float* __restrict__ gam,
                                   const float* __restrict__ bet,
                                   float* __restrict__ scale,
                                   float* __restrict__ shift, float inv_n) {
    int c = threadIdx.x;
    float m = sum[c] * inv_n;
    float var = sumsq[c] * inv_n - m * m;
    float sc = gam[c] * rsqrtf(var + 1e-5f);
    scale[c] = sc;
    shift[c] = bet[c] - m * sc;
}

// ---------- BN1 + ReLU applied in-place on y [b][p][co] bf16 ----------
__global__ __launch_bounds__(256) void bnpack_kernel(u32* __restrict__ y32,
                                                     const float* __restrict__ scale1,
                                                     const float* __restrict__ shift1) {
    const int b = blockIdx.x;
    const int t = threadIdx.x;
    const int c2 = (t & 127) * 2;           // u32 column -> co pair (constant per thread)
    const float s0 = scale1[c2],     s1 = scale1[c2 + 1];
    const float h0 = shift1[c2],     h1 = shift1[c2 + 1];
    u32* base = y32 + (size_t)b * 51200;    // 400 pos * 128 u32
    for (int q = 0; q < 200; ++q) {
        const int idx = t + q * 256;
        u32 v = base[idx];
        float a = fmaxf(0.f, fmaf(s0, bflo(v), h0));
        float c = fmaxf(0.f, fmaf(s1, bfhi(v), h1));
        base[idx] = (u32)f2bf(a) | ((u32)f2bf(c) << 16);
    }
}

// ---------- conv2: implicit-im2col bf16 MFMA GEMM, weight-reuse blocking ----------
// 512 blocks = 4 co-tiles x 128 image-groups of 4. ct4 = blockIdx&3 is constant
// per XCD under round-robin dispatch -> each XCD streams only its 5.3 MB weight
// slice (L2-resident) instead of all 21.2 MB from L3.
// Per (kk, 128-ci half): stage 4img x 36pos rows to LDS; wave = image.
// ccc/hi/lo accumulation order identical to previous round => bit-identical z.
__global__ __launch_bounds__(256) void conv2_mfma_kernel(const u16* __restrict__ y,
                                                         const u16* __restrict__ w2r,
                                                         const float* __restrict__ b2,
                                                         float* __restrict__ z_raw,
                                                         float* __restrict__ sum2,
                                                         float* __restrict__ sumsq2) {
    __shared__ __align__(16) u16 stg[156 * 136];   // 42.4 KB: row=img*36+pos (+12 pad rows), 128 ci + 8 pad
    const int ct4 = blockIdx.x & 3;                // co-tile: co in [ct4*64, ct4*64+64)
    const int g   = blockIdx.x >> 2;               // image-group of 4
    const int t = threadIdx.x;
    const int wave = t >> 6, lane = t & 63;
    const int n16 = lane & 15, quad = lane >> 4;
    const int bimg = g * 4 + wave;                 // this wave's image

    f32x4 zero = {0.f, 0.f, 0.f, 0.f};
    f32x4 acc[4][3];
#pragma unroll
    for (int ct = 0; ct < 4; ++ct)
#pragma unroll
        for (int pt = 0; pt < 3; ++pt) acc[ct][pt] = zero;

    const u16* yg = y + (size_t)g * 4 * 400 * 256;

    for (int kk = 0; kk < 81; ++kk) {
        const int kh = kk / 9, kw = kk - kh * 9;
        for (int cp = 0; cp < 2; ++cp) {
            __syncthreads();
            // stage 144 rows x 128 ci (2304 uint4, 9 per thread)
#pragma unroll
            for (int q = 0; q < 9; ++q) {
                const int v = t + q * 256;
                const int r = v >> 4, c16 = v & 15;
                const int img = (r * 456) >> 14;           // r/36 for r<144
                const int pos = r - img * 36;
                const int oh = (pos * 43) >> 8;            // pos/6 for pos<36
                const int ow = pos - oh * 6;
                const int ip = (2 * oh + kh) * 20 + (2 * ow + kw);
                const uint4 d = *((const uint4*)(yg + ((size_t)img * 400 + ip) * 256
                                                 + cp * 128 + c16 * 8));
                *((uint4*)(stg + r * 136 + c16 * 8)) = d;
            }
            __syncthreads();
            const u16* wk = w2r + (size_t)kk * 131072 + (size_t)cp * 4 * 16384
                          + (ct4 * 64 + n16) * 32 + quad * 8;
#pragma unroll
            for (int c2 = 0; c2 < 4; ++c2) {
                const u16* wa = wk + c2 * 16384;
                bf16x8 ah[4], al[4];
#pragma unroll
                for (int ct = 0; ct < 4; ++ct) {
                    ah[ct] = *((const bf16x8*)(wa + ct * 512));
                    al[ct] = *((const bf16x8*)(wa + 8192 + ct * 512));
                }
                bf16x8 bfr[3];
                const u16* pb = stg + (wave * 36 + n16) * 136 + c2 * 32 + quad * 8;
#pragma unroll
                for (int pt = 0; pt < 3; ++pt)
                    bfr[pt] = *((const bf16x8*)(pb + pt * 2176));   // 16 rows * 136
#pragma unroll
                for (int ct = 0; ct < 4; ++ct)
#pragma unroll
                    for (int pt = 0; pt < 3; ++pt) {
                        acc[ct][pt] = __builtin_amdgcn_mfma_f32_16x16x32_bf16(
                            ah[ct], bfr[pt], acc[ct][pt], 0, 0, 0);
                        acc[ct][pt] = __builtin_amdgcn_mfma_f32_16x16x32_bf16(
                            al[ct], bfr[pt], acc[ct][pt], 0, 0, 0);
                    }
            }
        }
    }

    // epilogue: bias, store z[bimg][co][36], BN2 stats (shfl-reduce over n16)
#pragma unroll
    for (int ct = 0; ct < 4; ++ct) {
#pragma unroll
        for (int r = 0; r < 4; ++r) {
            const int co = ct4 * 64 + ct * 16 + quad * 4 + r;
            const float bias = b2[co];
            float s = 0.f, ss = 0.f;
#pragma unroll
            for (int pt = 0; pt < 3; ++pt) {
                const int pos = pt * 16 + n16;
                if (pos < 36) {
                    float v = acc[ct][pt][r] + bias;
                    z_raw[((size_t)bimg * 256 + co) * 36 + pos] = v;
                    s += v; ss += v * v;
                }
            }
#pragma unroll
            for (int m = 1; m < 16; m <<= 1) {
                s  += __shfl_xor(s,  m, 64);
                ss += __shfl_xor(ss, m, 64);
            }
            if (n16 == 0) { atomicAdd(&sum2[co], s); atomicAdd(&sumsq2[co], ss); }
        }
    }
}

// ---------- BN2 + ReLU + capsule transpose: ut[b][d][i] f32, i = m*36+s, c = d*32+m ----------
__global__ __launch_bounds__(256) void ubuild_kernel(const float* __restrict__ z_raw,
                                                     const float* __restrict__ scale2,
                                                     const float* __restrict__ shift2,
                                                     float* __restrict__ ut) {
    const int b = blockIdx.x;
    const int t = threadIdx.x;            // c
    const int d = t >> 5, m = t & 31;
    const float sc = scale2[t], sh = shift2[t];
    const float4* zp = (const float4*)(z_raw + ((size_t)b * 256 + t) * 36);
    float4* up = (float4*)(ut + ((size_t)b * 8 + d) * 1152 + m * 36);
#pragma unroll
    for (int q = 0; q < 9; ++q) {
        float4 z = zp[q];
        float4 o;
        o.x = fmaxf(0.f, fmaf(sc, z.x, sh));
        o.y = fmaxf(0.f, fmaf(sc, z.y, sh));
        o.z = fmaxf(0.f, fmaf(sc, z.z, sh));
        o.w = fmaxf(0.f, fmaf(sc, z.w, sh));
        up[q] = o;
    }
}

// ---------- u_hat[b][i][je] bf16 = sum_d ut[b][d][i] * Wt2[i][je][d] ----------
// block: 8 images x 144-i chunk; W fragment held in regs across the 8-image loop
__global__ __launch_bounds__(256) void uhat_kernel(const float* __restrict__ ut,
                                                   const float* __restrict__ Wt2,
                                                   u16* __restrict__ u_hat) {
    __shared__ float utl[8 * 8 * 144];    // [bb][d][ii], 36 KB
    const int bg = blockIdx.x >> 3;       // 64 image-groups of 8
    const int ic = blockIdx.x & 7;        // 8 i-chunks of 144
    const int b0 = bg * 8, i0 = ic * 144;
    for (int v = threadIdx.x; v < 8 * 8 * 144; v += 256) {
        int ii = v % 144; int d = (v / 144) & 7; int bb = v / 1152;
        utl[v] = ut[(size_t)(b0 + bb) * 9216 + d * 1152 + i0 + ii];
    }
    __syncthreads();
    for (int q = 0; q < 90; ++q) {
        int o = q * 256 + threadIdx.x;    // 144*160 = 23040 = 90*256
        int ii = o / 160, je = o - ii * 160;
        const float* wp = Wt2 + ((size_t)(i0 + ii) * 160 + je) * 8;
        float w[8];
#pragma unroll
        for (int d = 0; d < 8; ++d) w[d] = wp[d];
#pragma unroll
        for (int bb = 0; bb < 8; ++bb) {
            float acc = 0.f;
#pragma unroll
            for (int d = 0; d < 8; ++d) acc = fmaf(w[d], utl[bb * 1152 + d * 144 + ii], acc);
            u_hat[(size_t)(b0 + bb) * 184320 + (size_t)(i0 + ii) * 160 + je] = f2bf(acc);
        }
    }
}

// ---------- fused 5-iteration routing: ONE u_hat pass per iteration ----------
// u_hat[b][i][je]; per block: 6 chunks of 192 i staged to LDS;
// phase A (per-i): b_log += u.v_prev, softmax -> c ; phase B (per-je): s += c*u
__global__ __launch_bounds__(384) void routing_kernel(const u16* __restrict__ u_hat,
                                                      float* __restrict__ out) {
    __shared__ __align__(16) u16 uhs[192 * 164];  // 192 rows x (320B data + 8B pad)
    __shared__ float cl[10 * 192];                // c[j][i_local]
    __shared__ float part[320];
    __shared__ float sv[160];                     // s then v
    const int b = blockIdx.x;
    const int t = threadIdx.x;
    const u16* uh = u_hat + (size_t)b * 184320;
    const int hB = (t < 320) ? (t / 160) : 0;
    const int je = (t < 320) ? (t - hB * 160) : 0;
    const int jB = je >> 4;

    // threads t<192 own i = c*192+t for each chunk c -> bl[6][10] in registers.
    float bl[6][10];
#pragma unroll
    for (int c = 0; c < 6; ++c)
#pragma unroll
        for (int j = 0; j < 10; ++j) bl[c][j] = 0.f;

    for (int k = 0; k < 5; ++k) {
        float sacc = 0.f;
        for (int c = 0; c < 6; ++c) {
            __syncthreads();               // uhs free (prev chunk's B / prev iter done)
            const u16* src = uh + (size_t)c * 30720;   // 192*160
#pragma unroll
            for (int q = 0; q < 20; ++q) {
                int v = t + q * 384;       // < 7680
                int r = v / 40, off = v - r * 40;
                uint2 d = *((const uint2*)(src + r * 160 + off * 4));
                *((uint2*)(uhs + r * 164 + off * 4)) = d;
            }
            __syncthreads();
            if (k > 0 && t < 192) {        // phase A
                const u16* row = uhs + t * 164;
                float bj[10];
#pragma unroll
                for (int j = 0; j < 10; ++j) {
                    float dj = 0.f;
#pragma unroll
                    for (int q = 0; q < 4; ++q) {
                        uint2 v2 = *((const uint2*)(row + j * 16 + q * 4));
                        dj += bflo(v2.x) * sv[j * 16 + q * 4]
                            + bfhi(v2.x) * sv[j * 16 + q * 4 + 1]
                            + bflo(v2.y) * sv[j * 16 + q * 4 + 2]
                            + bfhi(v2.y) * sv[j * 16 + q * 4 + 3];
                    }
                    bl[c][j] += dj;
                    bj[j] = bl[c][j];
                }
                float mx = bj[0];
#pragma unroll
                for (int j = 1; j < 10; ++j) mx = fmaxf(mx, bj[j]);
                float s = 0.f;
#pragma unroll
                for (int j = 0; j < 10; ++j) { bj[j] = __expf(bj[j] - mx); s += bj[j]; }
                float inv = 1.f / s;
#pragma unroll
                for (int j = 0; j < 10; ++j) cl[j * 192 + t] = bj[j] * inv;
            }
            __syncthreads();
            if (t < 320) {                 // phase B
                const int r0 = hB * 96;
                if (k == 0) {
                    float a = 0.f;
#pragma unroll 4
                    for (int il = 0; il < 96; ++il)
                        a += bf2f(uhs[(r0 + il) * 164 + je]);
                    sacc = fmaf(0.1f, a, sacc);
                } else {
#pragma unroll 4
                    for (int il = 0; il < 96; ++il) {
                        const int r = r0 + il;
                        sacc = fmaf(cl[jB * 192 + r], bf2f(uhs[r * 164 + je]), sacc);
                    }
                }
            }
        }
        __syncthreads();
        if (t < 320) part[t] = sacc;
        __syncthreads();
        if (t < 160) sv[t] = part[t] + part[t + 160];
        __syncthreads();
        if (t < 10) {
            float n2 = 0.f;
#pragma unroll
            for (int e2 = 0; e2 < 16; ++e2) { float xx = sv[t * 16 + e2]; n2 += xx * xx; }
            float n = sqrtf(n2);
            float f = n / (n2 + 1.f);
#pragma unroll
            for (int e2 = 0; e2 < 16; ++e2) sv[t * 16 + e2] *= f;
        }
        __syncthreads();
    }
    if (t < 160) out[(size_t)b * 160 + t] = sv[t];
}

extern "C" void kernel_launch(void* const* d_in, const int* in_sizes, int n_in,
                              void* d_out, int out_size, void* d_ws, size_t ws_size,
                              hipStream_t stream) {
    const float* x   = (const float*)d_in[0];
    const float* w1  = (const float*)d_in[1];
    const float* b1  = (const float*)d_in[2];
    const float* g1  = (const float*)d_in[3];
    const float* be1 = (const float*)d_in[4];
    const float* w2  = (const float*)d_in[5];
    const float* b2  = (const float*)d_in[6];
    const float* g2  = (const float*)d_in[7];
    const float* be2 = (const float*)d_in[8];
    const float* W   = (const float*)d_in[9];
    float* out = (float*)d_out;

    // ---- workspace layout (peak 213,524,480 B == proven-safe bound) ----
    // u_hat region [8K .. 188.75M) overlays y + w2r(hi/lo, 21.2MB) + z, all dead
    // before uhat_kernel writes u_hat (stream-ordered).
    const size_t OFF_UHAT = 8192;                       // 188,743,680 B
    const size_t OFF_Y    = 8192;                       // 104,857,600 B (in u_hat region)
    const size_t OFF_W2R  = 104865792ull;               //  21,233,664 B (in u_hat region)
    const size_t OFF_Z    = 126099456ull;               //  18,874,368 B (in u_hat region)
    const size_t OFF_UT   = 188751872ull;               //  18,874,368 B
    const size_t OFF_WT   = 207626240ull;               //   5,898,240 B
    const size_t WS_NEED  = 213524480ull;
    if (ws_size < WS_NEED) return;  // diagnostic: clean absmax-fail instead of page fault

    char* ws = (char*)d_ws;
    float* sum1   = (float*)(ws + 0);
    float* sumsq1 = (float*)(ws + 1024);
    float* sum2   = (float*)(ws + 2048);
    float* sumsq2 = (float*)(ws + 3072);
    float* scale1 = (float*)(ws + 4096);
    float* shift1 = (float*)(ws + 5120);
    float* scale2 = (float*)(ws + 6144);
    float* shift2 = (float*)(ws + 7168);
    u16*   y     = (u16*)(ws + OFF_Y);
    u16*   w2r   = (u16*)(ws + OFF_W2R);
    float* z_raw = (float*)(ws + OFF_Z);
    float* ut    = (float*)(ws + OFF_UT);
    float* Wt2   = (float*)(ws + OFF_WT);
    u16*   u_hat = (u16*)(ws + OFF_UHAT);

    hipMemsetAsync(ws, 0, 4096, stream);  // zero BN sum accumulators

    hipLaunchKernelGGL(repack_w2_kernel, dim3(41472), dim3(256), 0, stream, w2, w2r);
    hipLaunchKernelGGL(repack_W_kernel,  dim3(5760),  dim3(256), 0, stream, W, Wt2);
    hipLaunchKernelGGL(conv1_kernel,     dim3(512),   dim3(256), 0, stream,
                       x, w1, b1, y, sum1, sumsq1);
    hipLaunchKernelGGL(finalize_bn_kernel, dim3(1), dim3(256), 0, stream,
                       sum1, sumsq1, g1, be1, scale1, shift1, 1.f / 204800.f);
    hipLaunchKernelGGL(bnpack_kernel,    dim3(512),   dim3(256), 0, stream,
                       (u32*)y, scale1, shift1);
    hipLaunchKernelGGL(conv2_mfma_kernel, dim3(512),  dim3(256), 0, stream,
                       y, w2r, b2, z_raw, sum2, sumsq2);
    hipLaunchKernelGGL(finalize_bn_kernel, dim3(1), dim3(256), 0, stream,
                       sum2, sumsq2, g2, be2, scale2, shift2, 1.f / 18432.f);
    hipLaunchKernelGGL(ubuild_kernel,    dim3(512),   dim3(256), 0, stream,
                       z_raw, scale2, shift2, ut);
    hipLaunchKernelGGL(uhat_kernel,      dim3(512),   dim3(256), 0, stream, ut, Wt2, u_hat);
    hipLaunchKernelGGL(routing_kernel,   dim3(512),   dim3(384), 0, stream, u_hat, out);
}